// Round 9
// baseline (621.698 us; speedup 1.0000x reference)
//
#include <hip/hip_runtime.h>
#include <stdint.h>
#include <stddef.h>

#define N_TOK 4096
#define DM    1024
#define NHEAD 16
#define HD    64

typedef __attribute__((ext_vector_type(8)))  short bf16x8;
typedef __attribute__((ext_vector_type(4)))  short bf16x4;
typedef __attribute__((ext_vector_type(4)))  float f32x4;
typedef __attribute__((ext_vector_type(16))) float f32x16;

static __device__ __forceinline__ float bf2f(short u) {
  union { unsigned int i; float f; } c;
  c.i = ((unsigned int)(unsigned short)u) << 16;
  return c.f;
}
static __device__ __forceinline__ unsigned short f2bf(float f) {
  union { float f; unsigned int i; } c; c.f = f;
  unsigned int x = c.i;
  return (unsigned short)((x + 0x7fffu + ((x >> 16) & 1u)) >> 16);
}
static __device__ __forceinline__ unsigned int cvtpk(float lo, float hi) {
  unsigned int d;
  asm("v_cvt_pk_bf16_f32 %0, %1, %2" : "=v"(d) : "v"(lo), "v"(hi));
  return d;
}
static __device__ __forceinline__ void plswap(unsigned int& a, unsigned int& b) {
  asm("v_permlane32_swap_b32 %0, %1" : "+v"(a), "+v"(b));
}
#if __has_builtin(__builtin_amdgcn_exp2f)
#define EXP2(x) __builtin_amdgcn_exp2f(x)
#else
#define EXP2(x) exp2f(x)
#endif
// async global->LDS, 16B/lane; LDS dest wave-uniform base (HW adds lane*16)
static __device__ __forceinline__ void gload16(const void* g, void* l) {
  __builtin_amdgcn_global_load_lds(
      (const __attribute__((address_space(1))) unsigned int*)g,
      (__attribute__((address_space(3))) unsigned int*)l, 16, 0, 0);
}

// ---------------- fused fp32 -> bf16 conversion (all 7 tensors, 1 launch) ----------------
struct Cvt7 { const float* s[7]; unsigned short* d[7]; };
__global__ void cvt_all(Cvt7 a) {
  int u0 = blockIdx.x << 10;              // 1024 units per block, uniform segment
  int seg, off;
  if (u0 < 1572864) { seg = u0 >> 19; off = u0 & 524287; }
  else { int j = u0 - 1572864; seg = 3 + (j >> 17); off = j & 131071; }
  const float* s = a.s[seg];
  unsigned short* dd = a.d[seg];
  int t = off + threadIdx.x;
#pragma unroll
  for (int j = 0; j < 4; ++j, t += 256) {
    const f32x4* sp = (const f32x4*)(s + (size_t)t * 8);
    f32x4 x = sp[0], y = sp[1];
    bf16x8 o;
    o[0] = (short)f2bf(x[0]); o[1] = (short)f2bf(x[1]);
    o[2] = (short)f2bf(x[2]); o[3] = (short)f2bf(x[3]);
    o[4] = (short)f2bf(y[0]); o[5] = (short)f2bf(y[1]);
    o[6] = (short)f2bf(y[2]); o[7] = (short)f2bf(y[3]);
    *(bf16x8*)(dd + (size_t)t * 8) = o;
  }
}

// ---------------- GEMM core: C = A @ W^T + bias, (MI*32)M x 128N tile, dbuf ----------------
// modes: 0 = bf16 row-major out; 1 = f32 row-major out;
//        2 = per-head RMSNorm -> Kn[h][n][64] bf16;  3 = transpose -> Vt[h][d][n] bf16
template <int MI>
static __device__ __forceinline__ void gemm_core(
    const unsigned short* __restrict__ A,
    const unsigned short* __restrict__ W,
    const float* __restrict__ bias,
    unsigned short* __restrict__ Cb,
    float* __restrict__ Cf,
    const float* __restrict__ nw,
    int Nn, int K, int mode, int m0, int n0)
{
  __shared__ __align__(16) unsigned short At[2][MI * 1024];  // (MI*32) x 32
  __shared__ __align__(16) unsigned short Wt[2][128 * 32];
  const int tid  = threadIdx.x;
  const int wid  = tid >> 6, lane = tid & 63;
  const int lm   = lane & 15, lg = lane >> 4;
  const int wm   = (wid >> 1) * (MI * 16), wn = (wid & 1) * 64;
  const int CPW  = (MI * 2 + 8) / 4;       // chunks per wave

  f32x4 acc[MI][4];
#pragma unroll
  for (int i = 0; i < MI; ++i)
#pragma unroll
    for (int j = 0; j < 4; ++j) acc[i][j] = f32x4{0.f, 0.f, 0.f, 0.f};

  auto stage = [&](int b, int k0) {
#pragma unroll
    for (int i = 0; i < CPW; ++i) {
      int c = wid * CPW + i;
      if (c < MI * 2)
        gload16(A + (size_t)(m0 + c * 16 + (lane >> 2)) * K + k0 + (lane & 3) * 8,
                (char*)At + b * (MI * 2048) + c * 1024);
      else
        gload16(W + (size_t)(n0 + (c - MI * 2) * 16 + (lane >> 2)) * K + k0 + (lane & 3) * 8,
                (char*)Wt + b * 8192 + (c - MI * 2) * 1024);
    }
  };

  const int nk = K >> 5;
  stage(0, 0);
  __syncthreads();
  for (int kt = 0; kt < nk; ++kt) {
    const int cur = kt & 1;
    if (kt + 1 < nk) stage(cur ^ 1, (kt + 1) << 5);

    bf16x8 af[MI], bfr[4];
#pragma unroll
    for (int mi = 0; mi < MI; ++mi)
      af[mi] = *(const bf16x8*)&At[cur][(wm + mi * 16 + lm) * 32 + lg * 8];
#pragma unroll
    for (int ni = 0; ni < 4; ++ni)
      bfr[ni] = *(const bf16x8*)&Wt[cur][(wn + ni * 16 + lm) * 32 + lg * 8];
    __builtin_amdgcn_s_setprio(1);
#pragma unroll
    for (int mi = 0; mi < MI; ++mi)
#pragma unroll
      for (int ni = 0; ni < 4; ++ni)
        acc[mi][ni] = __builtin_amdgcn_mfma_f32_16x16x32_bf16(
            af[mi], bfr[ni], acc[mi][ni], 0, 0, 0);
    __builtin_amdgcn_s_setprio(0);
    __syncthreads();
  }

  float bv[4];
#pragma unroll
  for (int ni = 0; ni < 4; ++ni) bv[ni] = bias[n0 + wn + ni * 16 + lm];

  if (mode <= 1) {
#pragma unroll
    for (int mi = 0; mi < MI; ++mi)
#pragma unroll
      for (int ni = 0; ni < 4; ++ni) {
        int n = n0 + wn + ni * 16 + lm;
#pragma unroll
        for (int r = 0; r < 4; ++r) {
          int m = m0 + wm + mi * 16 + lg * 4 + r;
          float v = acc[mi][ni][r] + bv[ni];
          if (mode == 1) Cf[(size_t)m * Nn + n] = v;
          else           Cb[(size_t)m * Nn + n] = f2bf(v);
        }
      }
  } else if (mode == 2) {
    // K path: wave's 64 cols = one full head; fused RMSNorm over d
    const int h = (n0 + wn) >> 6;
    float w_[4];
#pragma unroll
    for (int ni = 0; ni < 4; ++ni) w_[ni] = nw[ni * 16 + lm];
#pragma unroll
    for (int mi = 0; mi < MI; ++mi) {
      float t[4][4], ssq[4];
#pragma unroll
      for (int ni = 0; ni < 4; ++ni)
#pragma unroll
        for (int r = 0; r < 4; ++r) t[ni][r] = acc[mi][ni][r] + bv[ni];
#pragma unroll
      for (int r = 0; r < 4; ++r)
        ssq[r] = t[0][r]*t[0][r] + t[1][r]*t[1][r] + t[2][r]*t[2][r] + t[3][r]*t[3][r];
#pragma unroll
      for (int r = 0; r < 4; ++r) {
        ssq[r] += __shfl_xor(ssq[r], 1);
        ssq[r] += __shfl_xor(ssq[r], 2);
        ssq[r] += __shfl_xor(ssq[r], 4);
        ssq[r] += __shfl_xor(ssq[r], 8);
      }
#pragma unroll
      for (int r = 0; r < 4; ++r) {
        float iv = rsqrtf(ssq[r] * (1.f / 64.f) + 1e-5f);
        int n_ = m0 + wm + mi * 16 + lg * 4 + r;
#pragma unroll
        for (int ni = 0; ni < 4; ++ni) {
          int d = ni * 16 + lm;
          Cb[(size_t)h * (N_TOK * HD) + (size_t)n_ * HD + d] = f2bf(t[ni][r] * w_[ni] * iv);
        }
      }
    }
  } else {
    // V path: transpose to Vt[h][d][n]
    const int h = (n0 + wn) >> 6;
#pragma unroll
    for (int mi = 0; mi < MI; ++mi)
#pragma unroll
      for (int ni = 0; ni < 4; ++ni) {
        int d  = ni * 16 + lm;
        int nb = m0 + wm + mi * 16 + lg * 4;
        bf16x4 o;
#pragma unroll
        for (int r = 0; r < 4; ++r) o[r] = (short)f2bf(acc[mi][ni][r] + bv[ni]);
        *(bf16x4*)&Cb[(size_t)h * (HD * N_TOK) + (size_t)d * N_TOK + nb] = o;
      }
  }
}

// fused QKV projections: grid (8, 32, 3), 128x128 tiles, z selects {q,k,v}
__global__ __launch_bounds__(256, 3) void qkv_gemm(
    const unsigned short* __restrict__ a0, const unsigned short* __restrict__ a1,
    const unsigned short* __restrict__ a2,
    const unsigned short* __restrict__ w0, const unsigned short* __restrict__ w1,
    const unsigned short* __restrict__ w2,
    const float* __restrict__ b0, const float* __restrict__ b1,
    const float* __restrict__ b2,
    unsigned short* __restrict__ o0, unsigned short* __restrict__ o1,
    unsigned short* __restrict__ o2,
    const float* __restrict__ knw)
{
  const int z = blockIdx.z;
  const unsigned short* A = (z == 0) ? a0 : (z == 1) ? a1 : a2;
  const unsigned short* W = (z == 0) ? w0 : (z == 1) ? w1 : w2;
  const float* B          = (z == 0) ? b0 : (z == 1) ? b1 : b2;
  unsigned short* O       = (z == 0) ? o0 : (z == 1) ? o1 : o2;
  const int mode          = (z == 0) ? 0 : (z == 1) ? 2 : 3;
  gemm_core<4>(A, W, B, O, nullptr, knw, DM, DM, mode,
               blockIdx.y * 128, blockIdx.x * 128);
}

// out-projection: f32 out, 128x128 tiles, grid (8, 32)
__global__ __launch_bounds__(256, 3) void out_gemm(
    const unsigned short* __restrict__ A, const unsigned short* __restrict__ W,
    const float* __restrict__ bias, float* __restrict__ Cf)
{
  gemm_core<4>(A, W, bias, nullptr, Cf, nullptr, DM, DM, 1,
               blockIdx.y * 128, blockIdx.x * 128);
}

// ---------------- fused RMSNorm(Q) + attention, swapped-QK 32x32 ----------------
// 1024-thread blocks: 16 waves = 4 kv-groups x 4 q-waves. KVBLK=32, q-tile 128/block.
// 2 blocks/CU (64KB LDS), 8 waves/SIMD. Softmax has NO max-shift (uniform scale
// cancels in P/sum(P); exp2 args bounded <=93).
__global__ __launch_bounds__(1024, 8) void attn_kernel(
    const unsigned short* __restrict__ qb,   // (n, 1024) bf16
    const unsigned short* __restrict__ kn,   // Kn[h][kv][64] bf16, normalized
    const unsigned short* __restrict__ vt,   // Vt[h][d][kv] bf16
    const float* __restrict__ wq,            // q_norm_w[64]
    unsigned short* __restrict__ ob)         // (n, 1024) bf16
{
  // [group][buf][K(4KB) | V(4KB)]: 64 KB total; +1.5 KB ls exchange
  __shared__ __align__(16) unsigned short SM[4][2][2][2048];
  __shared__ float lsm[384];

  // XCD-aware decode: XCD x owns heads {2x, 2x+1}
  const int wg   = blockIdx.x;
  const int x_   = wg & 7, rest = wg >> 3;     // rest 0..63
  const int h    = x_ * 2 + (rest & 1);
  const int qt   = rest >> 1;                  // 0..31
  const int tid  = threadIdx.x;
  const int wid  = tid >> 6, lane = tid & 63;
  const int g    = wid >> 2, wv = wid & 3;     // kv-group, q-wave
  const int l31  = lane & 31, hi = lane >> 5;
  const int sl   = l31 & 7;
  const int qbase = qt * 128 + wv * 32;

  // ---- Q fragments, RMSNorm fused, scaled by log2(e) ----
  bf16x8 qf[4];
  {
    const unsigned short* qp = qb + (size_t)(qbase + l31) * DM + h * HD + hi * 8;
    float qv[32]; float ss = 0.f;
#pragma unroll
    for (int s = 0; s < 4; ++s) {
      bf16x8 raw = *(const bf16x8*)(qp + s * 16);
#pragma unroll
      for (int j = 0; j < 8; ++j) { float f = bf2f(raw[j]); qv[s*8+j] = f; ss += f*f; }
    }
    ss += __shfl_xor(ss, 32);
    float inv = rsqrtf(ss * (1.f / 64.f) + 1e-5f) * 1.44269504f;
#pragma unroll
    for (int s = 0; s < 4; ++s)
#pragma unroll
      for (int j = 0; j < 8; ++j)
        qf[s][j] = (short)f2bf(qv[s*8+j] * wq[s*16 + hi*8 + j] * inv);
  }

  // K-read slots: d-slice s at ((2s+hi)^sl)<<4, row = l31 (128B rows, XOR swz)
  int slot[4];
#pragma unroll
  for (int x = 0; x < 4; ++x) slot[x] = (((2*x + hi) ^ sl) << 4);
  // V-read slots (paired-d 128B rows): row = (l31>>1), slot'' = (l31&1)*4 + ks*2 + hi
  int vs[2];
#pragma unroll
  for (int ks = 0; ks < 2; ++ks)
    vs[ks] = (((((l31 & 1) << 2) | (ks << 1) | hi) ^ ((l31 >> 1) & 7)) << 4);

  char* gbase = (char*)SM + g * 16384;
  const char* kRead = gbase + l31 * 128;
  const char* vRead = gbase + 4096 + (l31 >> 1) * 128;

  // staging sources (pre-swizzled global addrs). Per wave: 1 K-chunkKB + 1 V-chunkKB.
  const char* kgsrc;
  const char* vgsrc;
  char* kld = gbase + wv * 1024;
  char* vld = gbase + 4096 + wv * 1024;
  {
    const char* knb = (const char*)kn + (size_t)h * (N_TOK * HD * 2);
    const char* vtb = (const char*)vt + (size_t)h * (HD * N_TOK * 2);
    int c    = wv * 64 + lane;          // chunk 0..255
    int row  = c >> 3;                  // 0..31
    int sl2  = (c & 7) ^ (row & 7);
    kgsrc = knb + (size_t)(g * 1024 + row) * 128 + sl2 * 16;
    int d    = row * 2 + (sl2 >> 2);
    vgsrc = vtb + (size_t)d * (N_TOK * 2) + (size_t)(g * 1024) * 2 + (sl2 & 3) * 16;
  }

  f32x16 oacc[2], fz;
#pragma unroll
  for (int r = 0; r < 16; ++r) { oacc[0][r] = 0.f; oacc[1][r] = 0.f; fz[r] = 0.f; }
  float lsp[4] = {0.f, 0.f, 0.f, 0.f};

  // prologue: stage tile 0 into buf 0
  gload16(kgsrc, kld);
  gload16(vgsrc, vld);
  __syncthreads();

  const int NT = 1024 / 32;   // 32 tiles per kv-quarter
  for (int it = 0; it < NT; ++it) {
    const int cur = it & 1;
    if (it + 1 < NT) {
      const int nb = (cur ^ 1) * 8192;
      gload16(kgsrc + (size_t)(it + 1) * 4096, kld + nb);
      gload16(vgsrc + (size_t)(it + 1) * 64,   vld + nb);
    }
    const char* KB = kRead + cur * 8192;
    const char* VB = vRead + cur * 8192;

    // S^T = K Q^T over 32 kv x 32 q
    __builtin_amdgcn_s_setprio(1);
    bf16x8 kf0 = *(const bf16x8*)(KB + slot[0]);
    f32x16 sc = __builtin_amdgcn_mfma_f32_32x32x16_bf16(kf0, qf[0], fz, 0, 0, 0);
#pragma unroll
    for (int s = 1; s < 4; ++s) {
      bf16x8 kf = *(const bf16x8*)(KB + slot[s]);
      sc = __builtin_amdgcn_mfma_f32_32x32x16_bf16(kf, qf[s], sc, 0, 0, 0);
    }
    __builtin_amdgcn_s_setprio(0);
    // exp2 (no shift), pack, PV
    float e[16];
#pragma unroll
    for (int r = 0; r < 16; ++r) { e[r] = EXP2(sc[r]); lsp[r & 3] += e[r]; }
    unsigned int wpk[4][2];
#pragma unroll
    for (int b = 0; b < 4; ++b) {
      wpk[b][0] = cvtpk(e[4*b+0], e[4*b+1]);
      wpk[b][1] = cvtpk(e[4*b+2], e[4*b+3]);
    }
#pragma unroll
    for (int pr = 0; pr < 2; ++pr) {
      unsigned int x0 = wpk[2*pr][0], x1 = wpk[2*pr][1];
      unsigned int y0 = wpk[2*pr+1][0], y1 = wpk[2*pr+1][1];
      plswap(x0, y0);
      plswap(x1, y1);
      union { unsigned int u[4]; bf16x8 v; } pa;
      pa.u[0] = x0; pa.u[1] = x1; pa.u[2] = y0; pa.u[3] = y1;
      __builtin_amdgcn_s_setprio(1);
#pragma unroll
      for (int dt = 0; dt < 2; ++dt) {
        bf16x8 vf = *(const bf16x8*)(VB + dt * 2048 + vs[pr]);
        oacc[dt] = __builtin_amdgcn_mfma_f32_32x32x16_bf16(pa.v, vf, oacc[dt], 0, 0, 0);
      }
      __builtin_amdgcn_s_setprio(0);
    }
    __syncthreads();
  }

  // ---- 4-way kv-group merge via LDS tree, then bf16 write ----
  float ls = (lsp[0] + lsp[1]) + (lsp[2] + lsp[3]);
  ls += __shfl_xor(ls, 32);   // ls = sum over this group's kv for q = l31

  float* R0 = (float*)SM;                       // 32 KB
  float* R1 = (float*)((char*)SM + 32768);      // 32 KB
  const int idx  = wv * 64 + lane;              // 0..255
  const int lidx = wv * 32 + l31;               // 0..127

  // Phase A: g=1 -> R0, g=3 -> R1
  if (g == 1 || g == 3) {
    float* R = (g == 1) ? R0 : R1;
#pragma unroll
    for (int dt = 0; dt < 2; ++dt)
#pragma unroll
      for (int r = 0; r < 16; ++r)
        R[(dt * 16 + r) * 256 + idx] = oacc[dt][r];
    if (hi == 0) lsm[((g == 1) ? 0 : 128) + lidx] = ls;
  }
  __syncthreads();
  if (g == 0 || g == 2) {
    float* R = (g == 0) ? R0 : R1;
#pragma unroll
    for (int dt = 0; dt < 2; ++dt)
#pragma unroll
      for (int r = 0; r < 16; ++r)
        oacc[dt][r] += R[(dt * 16 + r) * 256 + idx];
    ls += lsm[((g == 0) ? 0 : 128) + lidx];
  }
  __syncthreads();
  // Phase B: g=2 -> R0
  if (g == 2) {
#pragma unroll
    for (int dt = 0; dt < 2; ++dt)
#pragma unroll
      for (int r = 0; r < 16; ++r)
        R0[(dt * 16 + r) * 256 + idx] = oacc[dt][r];
    if (hi == 0) lsm[256 + lidx] = ls;
  }
  __syncthreads();
  if (g == 0) {
#pragma unroll
    for (int dt = 0; dt < 2; ++dt)
#pragma unroll
      for (int r = 0; r < 16; ++r)
        oacc[dt][r] += R0[(dt * 16 + r) * 256 + idx];
    ls += lsm[256 + lidx];
    float il = 1.f / ls;
#pragma unroll
    for (int r = 0; r < 16; ++r) {
      int q = (r & 3) + 8 * (r >> 2) + 4 * hi;
      float ilr = __int_as_float(
          __builtin_amdgcn_ds_bpermute(q << 2, __float_as_int(il)));
      unsigned short* op = ob + (size_t)(qbase + q) * DM + h * HD + l31;
      op[0]  = f2bf(oacc[0][r] * ilr);
      op[32] = f2bf(oacc[1][r] * ilr);
    }
  }
}

// ---------------- host ----------------
extern "C" void kernel_launch(void* const* d_in, const int* in_sizes, int n_in,
                              void* d_out, int out_size, void* d_ws, size_t ws_size,
                              hipStream_t stream) {
  const float* query = (const float*)d_in[0];
  const float* key   = (const float*)d_in[1];
  const float* value = (const float*)d_in[2];
  const float* Wq    = (const float*)d_in[3];
  const float* bq    = (const float*)d_in[4];
  const float* Wk    = (const float*)d_in[5];
  const float* bk    = (const float*)d_in[6];
  const float* Wv    = (const float*)d_in[7];
  const float* bv    = (const float*)d_in[8];
  const float* Wo    = (const float*)d_in[9];
  const float* bo    = (const float*)d_in[10];
  const float* qnw   = (const float*)d_in[11];
  const float* knw   = (const float*)d_in[12];

  char* ws = (char*)d_ws;
  const size_t MB = 1024 * 1024;
  unsigned short* qpj = (unsigned short*)(ws + 0 * MB);
  unsigned short* Kn  = (unsigned short*)(ws + 8 * MB);
  unsigned short* Vt  = (unsigned short*)(ws + 16 * MB);
  unsigned short* wob = (unsigned short*)(ws + 24 * MB);
  unsigned short* wqb = (unsigned short*)(ws + 26 * MB);
  unsigned short* wkb = (unsigned short*)(ws + 28 * MB);
  unsigned short* wvb = (unsigned short*)(ws + 30 * MB);
  unsigned short* qbf = (unsigned short*)(ws + 32 * MB);
  unsigned short* kbf = (unsigned short*)(ws + 40 * MB);
  unsigned short* vbf = (unsigned short*)(ws + 48 * MB);
  unsigned short* apj = (unsigned short*)(ws + 56 * MB);

  Cvt7 ca;
  ca.s[0] = query; ca.d[0] = qbf;
  ca.s[1] = key;   ca.d[1] = kbf;
  ca.s[2] = value; ca.d[2] = vbf;
  ca.s[3] = Wq;    ca.d[3] = wqb;
  ca.s[4] = Wk;    ca.d[4] = wkb;
  ca.s[5] = Wv;    ca.d[5] = wvb;
  ca.s[6] = Wo;    ca.d[6] = wob;
  cvt_all<<<2048, 256, 0, stream>>>(ca);

  qkv_gemm<<<dim3(DM / 128, N_TOK / 128, 3), 256, 0, stream>>>(
      qbf, kbf, vbf, wqb, wkb, wvb, bq, bk, bv, qpj, Kn, Vt, knw);

  attn_kernel<<<512, 1024, 0, stream>>>(qpj, Kn, Vt, qnw, apj);

  out_gemm<<<dim3(DM / 128, N_TOK / 128), 256, 0, stream>>>(apj, wob, bo, (float*)d_out);
}

// Round 10
// 168.256 us; speedup vs baseline: 3.6949x; 3.6949x over previous
//
#include <hip/hip_runtime.h>
#include <stdint.h>
#include <stddef.h>

#define N_TOK 4096
#define DM    1024
#define NHEAD 16
#define HD    64

typedef __attribute__((ext_vector_type(8)))  short bf16x8;
typedef __attribute__((ext_vector_type(4)))  short bf16x4;
typedef __attribute__((ext_vector_type(4)))  float f32x4;
typedef __attribute__((ext_vector_type(16))) float f32x16;

static __device__ __forceinline__ float bf2f(short u) {
  union { unsigned int i; float f; } c;
  c.i = ((unsigned int)(unsigned short)u) << 16;
  return c.f;
}
static __device__ __forceinline__ unsigned short f2bf(float f) {
  union { float f; unsigned int i; } c; c.f = f;
  unsigned int x = c.i;
  return (unsigned short)((x + 0x7fffu + ((x >> 16) & 1u)) >> 16);
}
static __device__ __forceinline__ unsigned int cvtpk(float lo, float hi) {
  unsigned int d;
  asm("v_cvt_pk_bf16_f32 %0, %1, %2" : "=v"(d) : "v"(lo), "v"(hi));
  return d;
}
static __device__ __forceinline__ void plswap(unsigned int& a, unsigned int& b) {
  asm("v_permlane32_swap_b32 %0, %1" : "+v"(a), "+v"(b));
}
#if __has_builtin(__builtin_amdgcn_exp2f)
#define EXP2(x) __builtin_amdgcn_exp2f(x)
#else
#define EXP2(x) exp2f(x)
#endif
// async global->LDS, 16B/lane; LDS dest wave-uniform base (HW adds lane*16)
static __device__ __forceinline__ void gload16(const void* g, void* l) {
  __builtin_amdgcn_global_load_lds(
      (const __attribute__((address_space(1))) unsigned int*)g,
      (__attribute__((address_space(3))) unsigned int*)l, 16, 0, 0);
}

// ---------------- fused fp32 -> bf16 conversion (all 7 tensors, 1 launch) ----------------
struct Cvt7 { const float* s[7]; unsigned short* d[7]; };
__global__ void cvt_all(Cvt7 a) {
  int u0 = blockIdx.x << 10;              // 1024 units per block, uniform segment
  int seg, off;
  if (u0 < 1572864) { seg = u0 >> 19; off = u0 & 524287; }
  else { int j = u0 - 1572864; seg = 3 + (j >> 17); off = j & 131071; }
  const float* s = a.s[seg];
  unsigned short* dd = a.d[seg];
  int t = off + threadIdx.x;
#pragma unroll
  for (int j = 0; j < 4; ++j, t += 256) {
    const f32x4* sp = (const f32x4*)(s + (size_t)t * 8);
    f32x4 x = sp[0], y = sp[1];
    bf16x8 o;
    o[0] = (short)f2bf(x[0]); o[1] = (short)f2bf(x[1]);
    o[2] = (short)f2bf(x[2]); o[3] = (short)f2bf(x[3]);
    o[4] = (short)f2bf(y[0]); o[5] = (short)f2bf(y[1]);
    o[6] = (short)f2bf(y[2]); o[7] = (short)f2bf(y[3]);
    *(bf16x8*)(dd + (size_t)t * 8) = o;
  }
}

// ---------------- GEMM core: C = A @ W^T + bias, (MI*32)M x 128N tile, dbuf ----------------
// modes: 0 = bf16 row-major out; 1 = f32 row-major out;
//        2 = per-head RMSNorm -> Kn[h][n][64] bf16;  3 = transpose -> Vt[h][d][n] bf16
template <int MI>
static __device__ __forceinline__ void gemm_core(
    const unsigned short* __restrict__ A,
    const unsigned short* __restrict__ W,
    const float* __restrict__ bias,
    unsigned short* __restrict__ Cb,
    float* __restrict__ Cf,
    const float* __restrict__ nw,
    int Nn, int K, int mode, int m0, int n0)
{
  __shared__ __align__(16) unsigned short At[2][MI * 1024];  // (MI*32) x 32
  __shared__ __align__(16) unsigned short Wt[2][128 * 32];
  const int tid  = threadIdx.x;
  const int wid  = tid >> 6, lane = tid & 63;
  const int lm   = lane & 15, lg = lane >> 4;
  const int wm   = (wid >> 1) * (MI * 16), wn = (wid & 1) * 64;
  const int CPW  = (MI * 2 + 8) / 4;       // chunks per wave

  f32x4 acc[MI][4];
#pragma unroll
  for (int i = 0; i < MI; ++i)
#pragma unroll
    for (int j = 0; j < 4; ++j) acc[i][j] = f32x4{0.f, 0.f, 0.f, 0.f};

  auto stage = [&](int b, int k0) {
#pragma unroll
    for (int i = 0; i < CPW; ++i) {
      int c = wid * CPW + i;
      if (c < MI * 2)
        gload16(A + (size_t)(m0 + c * 16 + (lane >> 2)) * K + k0 + (lane & 3) * 8,
                (char*)At + b * (MI * 2048) + c * 1024);
      else
        gload16(W + (size_t)(n0 + (c - MI * 2) * 16 + (lane >> 2)) * K + k0 + (lane & 3) * 8,
                (char*)Wt + b * 8192 + (c - MI * 2) * 1024);
    }
  };

  const int nk = K >> 5;
  stage(0, 0);
  __syncthreads();
  for (int kt = 0; kt < nk; ++kt) {
    const int cur = kt & 1;
    if (kt + 1 < nk) stage(cur ^ 1, (kt + 1) << 5);

    bf16x8 af[MI], bfr[4];
#pragma unroll
    for (int mi = 0; mi < MI; ++mi)
      af[mi] = *(const bf16x8*)&At[cur][(wm + mi * 16 + lm) * 32 + lg * 8];
#pragma unroll
    for (int ni = 0; ni < 4; ++ni)
      bfr[ni] = *(const bf16x8*)&Wt[cur][(wn + ni * 16 + lm) * 32 + lg * 8];
    __builtin_amdgcn_s_setprio(1);
#pragma unroll
    for (int mi = 0; mi < MI; ++mi)
#pragma unroll
      for (int ni = 0; ni < 4; ++ni)
        acc[mi][ni] = __builtin_amdgcn_mfma_f32_16x16x32_bf16(
            af[mi], bfr[ni], acc[mi][ni], 0, 0, 0);
    __builtin_amdgcn_s_setprio(0);
    __syncthreads();
  }

  float bv[4];
#pragma unroll
  for (int ni = 0; ni < 4; ++ni) bv[ni] = bias[n0 + wn + ni * 16 + lm];

  if (mode <= 1) {
#pragma unroll
    for (int mi = 0; mi < MI; ++mi)
#pragma unroll
      for (int ni = 0; ni < 4; ++ni) {
        int n = n0 + wn + ni * 16 + lm;
#pragma unroll
        for (int r = 0; r < 4; ++r) {
          int m = m0 + wm + mi * 16 + lg * 4 + r;
          float v = acc[mi][ni][r] + bv[ni];
          if (mode == 1) Cf[(size_t)m * Nn + n] = v;
          else           Cb[(size_t)m * Nn + n] = f2bf(v);
        }
      }
  } else if (mode == 2) {
    // K path: wave's 64 cols = one full head; fused RMSNorm over d
    const int h = (n0 + wn) >> 6;
    float w_[4];
#pragma unroll
    for (int ni = 0; ni < 4; ++ni) w_[ni] = nw[ni * 16 + lm];
#pragma unroll
    for (int mi = 0; mi < MI; ++mi) {
      float t[4][4], ssq[4];
#pragma unroll
      for (int ni = 0; ni < 4; ++ni)
#pragma unroll
        for (int r = 0; r < 4; ++r) t[ni][r] = acc[mi][ni][r] + bv[ni];
#pragma unroll
      for (int r = 0; r < 4; ++r)
        ssq[r] = t[0][r]*t[0][r] + t[1][r]*t[1][r] + t[2][r]*t[2][r] + t[3][r]*t[3][r];
#pragma unroll
      for (int r = 0; r < 4; ++r) {
        ssq[r] += __shfl_xor(ssq[r], 1);
        ssq[r] += __shfl_xor(ssq[r], 2);
        ssq[r] += __shfl_xor(ssq[r], 4);
        ssq[r] += __shfl_xor(ssq[r], 8);
      }
#pragma unroll
      for (int r = 0; r < 4; ++r) {
        float iv = rsqrtf(ssq[r] * (1.f / 64.f) + 1e-5f);
        int n_ = m0 + wm + mi * 16 + lg * 4 + r;
#pragma unroll
        for (int ni = 0; ni < 4; ++ni) {
          int d = ni * 16 + lm;
          Cb[(size_t)h * (N_TOK * HD) + (size_t)n_ * HD + d] = f2bf(t[ni][r] * w_[ni] * iv);
        }
      }
    }
  } else {
    // V path: transpose to Vt[h][d][n]
    const int h = (n0 + wn) >> 6;
#pragma unroll
    for (int mi = 0; mi < MI; ++mi)
#pragma unroll
      for (int ni = 0; ni < 4; ++ni) {
        int d  = ni * 16 + lm;
        int nb = m0 + wm + mi * 16 + lg * 4;
        bf16x4 o;
#pragma unroll
        for (int r = 0; r < 4; ++r) o[r] = (short)f2bf(acc[mi][ni][r] + bv[ni]);
        *(bf16x4*)&Cb[(size_t)h * (HD * N_TOK) + (size_t)d * N_TOK + nb] = o;
      }
  }
}

// fused QKV projections: grid (8, 32, 3), 128x128 tiles, z selects {q,k,v}
__global__ __launch_bounds__(256, 3) void qkv_gemm(
    const unsigned short* __restrict__ a0, const unsigned short* __restrict__ a1,
    const unsigned short* __restrict__ a2,
    const unsigned short* __restrict__ w0, const unsigned short* __restrict__ w1,
    const unsigned short* __restrict__ w2,
    const float* __restrict__ b0, const float* __restrict__ b1,
    const float* __restrict__ b2,
    unsigned short* __restrict__ o0, unsigned short* __restrict__ o1,
    unsigned short* __restrict__ o2,
    const float* __restrict__ knw)
{
  const int z = blockIdx.z;
  const unsigned short* A = (z == 0) ? a0 : (z == 1) ? a1 : a2;
  const unsigned short* W = (z == 0) ? w0 : (z == 1) ? w1 : w2;
  const float* B          = (z == 0) ? b0 : (z == 1) ? b1 : b2;
  unsigned short* O       = (z == 0) ? o0 : (z == 1) ? o1 : o2;
  const int mode          = (z == 0) ? 0 : (z == 1) ? 2 : 3;
  gemm_core<4>(A, W, B, O, nullptr, knw, DM, DM, mode,
               blockIdx.y * 128, blockIdx.x * 128);
}

// out-projection: f32 out, 128x128 tiles, grid (8, 32)
__global__ __launch_bounds__(256, 3) void out_gemm(
    const unsigned short* __restrict__ A, const unsigned short* __restrict__ W,
    const float* __restrict__ bias, float* __restrict__ Cf)
{
  gemm_core<4>(A, W, bias, nullptr, Cf, nullptr, DM, DM, 1,
               blockIdx.y * 128, blockIdx.x * 128);
}

// ---------------- fused RMSNorm(Q) + attention, swapped-QK 32x32 ----------------
// Independent 256-thread blocks: 4 q-waves, one kv-half per block (split 2).
// grid 1024; LDS 32 KB -> 5 blocks/CU (20 waves/CU). Partials merged by merge_kernel.
// Softmax has NO max-shift: uniform scale cancels in P/sum(P); exp2 args bounded (<=93).
__global__ __launch_bounds__(256, 5) void attn_kernel(
    const unsigned short* __restrict__ qb,   // (n, 1024) bf16
    const unsigned short* __restrict__ kn,   // Kn[h][kv][64] bf16, normalized
    const unsigned short* __restrict__ vt,   // Vt[h][d][kv] bf16
    const float* __restrict__ wq,            // q_norm_w[64]
    unsigned short* __restrict__ opart,      // [2][4096][1024] bf16 partial O
    float* __restrict__ lpart)               // [2][16][4096] f32 partial rowsum
{
  // [buf][K(8KB) | V(8KB)]: 32 KB
  __shared__ __align__(16) unsigned short SM[2][2][4096];

  // XCD-aware decode: XCD x owns heads {2x, 2x+1}
  const int wg   = blockIdx.x;                 // 0..1023
  const int x_   = wg & 7, rest = wg >> 3;     // rest 0..127
  const int h    = x_ * 2 + (rest & 1);
  const int sp   = (rest >> 1) & 1;            // kv half
  const int qt   = rest >> 2;                  // 0..31
  const int tid  = threadIdx.x;
  const int wid  = tid >> 6, lane = tid & 63;
  const int l31  = lane & 31, hi = lane >> 5;
  const int sl   = l31 & 7;
  const int qbase = qt * 128 + wid * 32;

  // ---- Q fragments, RMSNorm fused, scaled by log2(e) ----
  bf16x8 qf[4];
  {
    const unsigned short* qp = qb + (size_t)(qbase + l31) * DM + h * HD + hi * 8;
    float qv[32]; float ss = 0.f;
#pragma unroll
    for (int s = 0; s < 4; ++s) {
      bf16x8 raw = *(const bf16x8*)(qp + s * 16);
#pragma unroll
      for (int j = 0; j < 8; ++j) { float f = bf2f(raw[j]); qv[s*8+j] = f; ss += f*f; }
    }
    ss += __shfl_xor(ss, 32);
    float inv = rsqrtf(ss * (1.f / 64.f) + 1e-5f) * 1.44269504f;
#pragma unroll
    for (int s = 0; s < 4; ++s)
#pragma unroll
      for (int j = 0; j < 8; ++j)
        qf[s][j] = (short)f2bf(qv[s*8+j] * wq[s*16 + hi*8 + j] * inv);
  }

  int slot[4];
#pragma unroll
  for (int x = 0; x < 4; ++x) slot[x] = (((2*x + hi) ^ sl) << 4);
  const char* base = (const char*)SM + l31 * 128;

  // staging sources (pre-swizzled global addresses), 4 chunks/wave
  const char* gsrc[4];
  char*       ldst[4];
  long        gstep[4];
  {
    const char* knb = (const char*)kn + (size_t)h * (N_TOK * HD * 2);
    const char* vtb = (const char*)vt + (size_t)h * (HD * N_TOK * 2);
#pragma unroll
    for (int i = 0; i < 4; ++i) {
      int chunk = wid * 4 + i;           // 0..7 K, 8..15 V
      int off   = (chunk & 7) * 1024 + lane * 16;
      int row   = off >> 7;
      int scol  = (off & 127) ^ ((row & 7) << 4);
      if (chunk < 8) {
        gsrc[i]  = knb + (size_t)(sp * 2048 + row) * 128 + scol;
        gstep[i] = 64 * 128;
        ldst[i]  = (char*)SM + (chunk & 7) * 1024;
      } else {
        gsrc[i]  = vtb + (size_t)row * (N_TOK * 2) + sp * 4096 + scol;
        gstep[i] = 64 * 2;
        ldst[i]  = (char*)SM + 8192 + (chunk & 7) * 1024;
      }
    }
  }

  f32x16 oacc[2], fz;
#pragma unroll
  for (int r = 0; r < 16; ++r) { oacc[0][r] = 0.f; oacc[1][r] = 0.f; fz[r] = 0.f; }
  float lsp[4] = {0.f, 0.f, 0.f, 0.f};

  // prologue: stage tile 0 into buf 0
#pragma unroll
  for (int i = 0; i < 4; ++i) { gload16(gsrc[i], ldst[i]); gsrc[i] += gstep[i]; }
  __syncthreads();

  const int NT = 2048 / 64;
  for (int it = 0; it < NT; ++it) {
    const int cur = it & 1;
    if (it + 1 < NT) {
      const int nb = cur ^ 1;
#pragma unroll
      for (int i = 0; i < 4; ++i) {
        gload16(gsrc[i], ldst[i] + nb * 16384);
        gsrc[i] += gstep[i];
      }
    }
    const char* KB = base + cur * 16384;
    const char* VB = KB + 8192;

#pragma unroll
    for (int kt = 0; kt < 2; ++kt) {
      // S^T = K Q^T over 32 kv x 32 q
      __builtin_amdgcn_s_setprio(1);
      bf16x8 kf0 = *(const bf16x8*)(KB + kt * 4096 + slot[0]);
      f32x16 sc = __builtin_amdgcn_mfma_f32_32x32x16_bf16(kf0, qf[0], fz, 0, 0, 0);
#pragma unroll
      for (int s = 1; s < 4; ++s) {
        bf16x8 kf = *(const bf16x8*)(KB + kt * 4096 + slot[s]);
        sc = __builtin_amdgcn_mfma_f32_32x32x16_bf16(kf, qf[s], sc, 0, 0, 0);
      }
      __builtin_amdgcn_s_setprio(0);
      // exp2 (no shift), pack, PV
      float e[16];
#pragma unroll
      for (int r = 0; r < 16; ++r) { e[r] = EXP2(sc[r]); lsp[r & 3] += e[r]; }
      unsigned int wpk[4][2];
#pragma unroll
      for (int b = 0; b < 4; ++b) {
        wpk[b][0] = cvtpk(e[4*b+0], e[4*b+1]);
        wpk[b][1] = cvtpk(e[4*b+2], e[4*b+3]);
      }
#pragma unroll
      for (int pr = 0; pr < 2; ++pr) {
        unsigned int x0 = wpk[2*pr][0], x1 = wpk[2*pr][1];
        unsigned int y0 = wpk[2*pr+1][0], y1 = wpk[2*pr+1][1];
        plswap(x0, y0);
        plswap(x1, y1);
        union { unsigned int u[4]; bf16x8 v; } pa;
        pa.u[0] = x0; pa.u[1] = x1; pa.u[2] = y0; pa.u[3] = y1;
        int ks = kt * 2 + pr;
        __builtin_amdgcn_s_setprio(1);
#pragma unroll
        for (int dt = 0; dt < 2; ++dt) {
          bf16x8 vf = *(const bf16x8*)(VB + dt * 4096 + slot[ks]);
          oacc[dt] = __builtin_amdgcn_mfma_f32_32x32x16_bf16(pa.v, vf, oacc[dt], 0, 0, 0);
        }
        __builtin_amdgcn_s_setprio(0);
      }
    }
    __syncthreads();
  }

  // ---- epilogue: write bf16 O-partials + f32 rowsum partial ----
  float ls = (lsp[0] + lsp[1]) + (lsp[2] + lsp[3]);
  ls += __shfl_xor(ls, 32);
  unsigned short* Opb = opart + (size_t)sp * (N_TOK * DM);
#pragma unroll
  for (int r = 0; r < 16; ++r) {
    int q = (r & 3) + 8 * (r >> 2) + 4 * hi;
    unsigned short* p = Opb + (size_t)(qbase + q) * DM + h * HD + l31;
    p[0]  = f2bf(oacc[0][r]);
    p[32] = f2bf(oacc[1][r]);
  }
  if (hi == 0)
    lpart[(size_t)sp * (NHEAD * N_TOK) + h * N_TOK + qbase + l31] = ls;
}

// ---------------- merge: apj = (O0 + O1) / (l0 + l1), bf16 ----------------
__global__ void merge_kernel(const unsigned short* __restrict__ opart,
                             const float* __restrict__ lpart,
                             unsigned short* __restrict__ am)
{
  int i = (blockIdx.x * 256 + threadIdx.x) * 8;   // 8 consecutive cols, same head
  int n = i >> 10, c = i & 1023, h = c >> 6;
  float l = lpart[h * N_TOK + n] + lpart[NHEAD * N_TOK + h * N_TOK + n];
  float il = 1.f / l;
  bf16x8 a = *(const bf16x8*)(opart + (size_t)n * DM + c);
  bf16x8 b = *(const bf16x8*)(opart + (size_t)(N_TOK * DM) + (size_t)n * DM + c);
  bf16x8 o;
#pragma unroll
  for (int j = 0; j < 8; ++j)
    o[j] = (short)f2bf((bf2f(a[j]) + bf2f(b[j])) * il);
  *(bf16x8*)(am + i) = o;
}

// ---------------- host ----------------
extern "C" void kernel_launch(void* const* d_in, const int* in_sizes, int n_in,
                              void* d_out, int out_size, void* d_ws, size_t ws_size,
                              hipStream_t stream) {
  const float* query = (const float*)d_in[0];
  const float* key   = (const float*)d_in[1];
  const float* value = (const float*)d_in[2];
  const float* Wq    = (const float*)d_in[3];
  const float* bq    = (const float*)d_in[4];
  const float* Wk    = (const float*)d_in[5];
  const float* bk    = (const float*)d_in[6];
  const float* Wv    = (const float*)d_in[7];
  const float* bv    = (const float*)d_in[8];
  const float* Wo    = (const float*)d_in[9];
  const float* bo    = (const float*)d_in[10];
  const float* qnw   = (const float*)d_in[11];
  const float* knw   = (const float*)d_in[12];

  char* ws = (char*)d_ws;
  const size_t MB = 1024 * 1024;
  // 0..8 qpj | 8..16 Kn | 16..24 Vt | 24..26 wob | 26..28 wqb | 28..30 wkb | 30..32 wvb
  // 32..40 qbf | 40..48 kbf | 48..56 vbf | 56..64 apj
  // after qkv_gemm, qbf/kbf/vbf are dead: 32..48 Opart (bf16 x2 halves), 48..48.5 Lpart
  unsigned short* qpj = (unsigned short*)(ws + 0 * MB);
  unsigned short* Kn  = (unsigned short*)(ws + 8 * MB);
  unsigned short* Vt  = (unsigned short*)(ws + 16 * MB);
  unsigned short* wob = (unsigned short*)(ws + 24 * MB);
  unsigned short* wqb = (unsigned short*)(ws + 26 * MB);
  unsigned short* wkb = (unsigned short*)(ws + 28 * MB);
  unsigned short* wvb = (unsigned short*)(ws + 30 * MB);
  unsigned short* qbf = (unsigned short*)(ws + 32 * MB);
  unsigned short* kbf = (unsigned short*)(ws + 40 * MB);
  unsigned short* vbf = (unsigned short*)(ws + 48 * MB);
  unsigned short* apj = (unsigned short*)(ws + 56 * MB);
  unsigned short* Op  = (unsigned short*)(ws + 32 * MB);
  float*          Lp  = (float*)(ws + 48 * MB);

  Cvt7 ca;
  ca.s[0] = query; ca.d[0] = qbf;
  ca.s[1] = key;   ca.d[1] = kbf;
  ca.s[2] = value; ca.d[2] = vbf;
  ca.s[3] = Wq;    ca.d[3] = wqb;
  ca.s[4] = Wk;    ca.d[4] = wkb;
  ca.s[5] = Wv;    ca.d[5] = wvb;
  ca.s[6] = Wo;    ca.d[6] = wob;
  cvt_all<<<2048, 256, 0, stream>>>(ca);

  qkv_gemm<<<dim3(DM / 128, N_TOK / 128, 3), 256, 0, stream>>>(
      qbf, kbf, vbf, wqb, wkb, wvb, bq, bk, bv, qpj, Kn, Vt, knw);

  attn_kernel<<<1024, 256, 0, stream>>>(qpj, Kn, Vt, qnw, Op, Lp);

  merge_kernel<<<N_TOK * DM / 8 / 256, 256, 0, stream>>>(Op, Lp, apj);

  out_gemm<<<dim3(DM / 128, N_TOK / 128), 256, 0, stream>>>(apj, wob, bo, (float*)d_out);
}

// Round 11
// 165.525 us; speedup vs baseline: 3.7559x; 1.0165x over previous
//
#include <hip/hip_runtime.h>
#include <stdint.h>
#include <stddef.h>

#define N_TOK 4096
#define DM    1024
#define NHEAD 16
#define HD    64

typedef __attribute__((ext_vector_type(8)))  short bf16x8;
typedef __attribute__((ext_vector_type(4)))  short bf16x4;
typedef __attribute__((ext_vector_type(4)))  float f32x4;
typedef __attribute__((ext_vector_type(16))) float f32x16;

static __device__ __forceinline__ float bf2f(short u) {
  union { unsigned int i; float f; } c;
  c.i = ((unsigned int)(unsigned short)u) << 16;
  return c.f;
}
static __device__ __forceinline__ unsigned short f2bf(float f) {
  union { float f; unsigned int i; } c; c.f = f;
  unsigned int x = c.i;
  return (unsigned short)((x + 0x7fffu + ((x >> 16) & 1u)) >> 16);
}
static __device__ __forceinline__ unsigned int cvtpk(float lo, float hi) {
  unsigned int d;
  asm("v_cvt_pk_bf16_f32 %0, %1, %2" : "=v"(d) : "v"(lo), "v"(hi));
  return d;
}
static __device__ __forceinline__ void plswap(unsigned int& a, unsigned int& b) {
  asm("v_permlane32_swap_b32 %0, %1" : "+v"(a), "+v"(b));
}
#if __has_builtin(__builtin_amdgcn_exp2f)
#define EXP2(x) __builtin_amdgcn_exp2f(x)
#else
#define EXP2(x) exp2f(x)
#endif
// async global->LDS, 16B/lane; LDS dest wave-uniform base (HW adds lane*16)
static __device__ __forceinline__ void gload16(const void* g, void* l) {
  __builtin_amdgcn_global_load_lds(
      (const __attribute__((address_space(1))) unsigned int*)g,
      (__attribute__((address_space(3))) unsigned int*)l, 16, 0, 0);
}

// ---------------- fp32 -> bf16 conversion (weights only, 1 launch) ----------------
struct Cvt4 { const float* s[4]; unsigned short* d[4]; };
__global__ void cvt_w(Cvt4 a) {
  int u0 = blockIdx.x << 10;              // 1024 units/block; 131072 units per seg
  int seg = u0 >> 17, off = u0 & 131071;
  const float* s = a.s[seg];
  unsigned short* dd = a.d[seg];
  int t = off + threadIdx.x;
#pragma unroll
  for (int j = 0; j < 4; ++j, t += 256) {
    const f32x4* sp = (const f32x4*)(s + (size_t)t * 8);
    f32x4 x = sp[0], y = sp[1];
    bf16x8 o;
    o[0] = (short)f2bf(x[0]); o[1] = (short)f2bf(x[1]);
    o[2] = (short)f2bf(x[2]); o[3] = (short)f2bf(x[3]);
    o[4] = (short)f2bf(y[0]); o[5] = (short)f2bf(y[1]);
    o[6] = (short)f2bf(y[2]); o[7] = (short)f2bf(y[3]);
    *(bf16x8*)(dd + (size_t)t * 8) = o;
  }
}

// ---------------- GEMM core: C = A @ W^T + bias, (MI*32)M x 128N tile, dbuf ----------------
// AF32: A is fp32, staged raw and converted to bf16 at the LDS->frag read
// (XOR-swizzled rows, pre-swizzled global source). W always bf16.
// modes: 0 = bf16 row-major out; 1 = f32 row-major out;
//        2 = per-head RMSNorm -> Kn[h][n][64] bf16;  3 = transpose -> Vt[h][d][n] bf16
template <int MI, bool AF32>
static __device__ __forceinline__ void gemm_core(
    const unsigned short* __restrict__ A,
    const float* __restrict__ A32,
    const unsigned short* __restrict__ W,
    const float* __restrict__ bias,
    unsigned short* __restrict__ Cb,
    float* __restrict__ Cf,
    const float* __restrict__ nw,
    int Nn, int K, int mode, int m0, int n0)
{
  // A tile: (MI*32) rows x 32 k; bf16 = MI*2KB/buf, fp32 = MI*4KB/buf
  __shared__ __align__(16) unsigned short At[2][MI * (AF32 ? 2048 : 1024)];
  __shared__ __align__(16) unsigned short Wt[2][128 * 32];
  const int tid  = threadIdx.x;
  const int wid  = tid >> 6, lane = tid & 63;
  const int lm   = lane & 15, lg = lane >> 4;
  const int wm   = (wid >> 1) * (MI * 16), wn = (wid & 1) * 64;
  const int NCA  = AF32 ? MI * 4 : MI * 2;   // A chunks (1KB) per buf
  const int CPW  = (NCA + 8) / 4;            // chunks per wave
  const int ABUF = MI * (AF32 ? 4096 : 2048);

  f32x4 acc[MI][4];
#pragma unroll
  for (int i = 0; i < MI; ++i)
#pragma unroll
    for (int j = 0; j < 4; ++j) acc[i][j] = f32x4{0.f, 0.f, 0.f, 0.f};

  auto stage = [&](int b, int k0) {
#pragma unroll
    for (int i = 0; i < CPW; ++i) {
      int c = wid * CPW + i;
      if (c < NCA) {
        if constexpr (AF32) {
          // fp32 rows are 128B; chunk = 2 rows; swizzle ^(row&7)<<4
          int off  = c * 1024 + lane * 16;
          int row  = off >> 7;
          int scol = (off & 127) ^ ((row & 7) << 4);
          gload16(A32 + (size_t)(m0 + row) * K + k0 + (scol >> 2),
                  (char*)At + b * ABUF + c * 1024);
        } else {
          gload16(A + (size_t)(m0 + c * 16 + (lane >> 2)) * K + k0 + (lane & 3) * 8,
                  (char*)At + b * ABUF + c * 1024);
        }
      } else {
        int cw = c - NCA;
        gload16(W + (size_t)(n0 + cw * 16 + (lane >> 2)) * K + k0 + (lane & 3) * 8,
                (char*)Wt + b * 8192 + cw * 1024);
      }
    }
  };

  const int nk = K >> 5;
  stage(0, 0);
  __syncthreads();
  for (int kt = 0; kt < nk; ++kt) {
    const int cur = kt & 1;
    if (kt + 1 < nk) stage(cur ^ 1, (kt + 1) << 5);

    bf16x8 af[MI], bfr[4];
#pragma unroll
    for (int mi = 0; mi < MI; ++mi) {
      if constexpr (AF32) {
        int arow = wm + mi * 16 + lm;
        const char* ab = (char*)At + cur * ABUF + arow * 128;
        int swz = (arow & 7) << 4;
        f32x4 a0 = *(const f32x4*)(ab + ((lg * 32) ^ swz));
        f32x4 a1 = *(const f32x4*)(ab + ((lg * 32 + 16) ^ swz));
        union { unsigned int u[4]; bf16x8 v; } p;
        p.u[0] = cvtpk(a0[0], a0[1]); p.u[1] = cvtpk(a0[2], a0[3]);
        p.u[2] = cvtpk(a1[0], a1[1]); p.u[3] = cvtpk(a1[2], a1[3]);
        af[mi] = p.v;
      } else {
        af[mi] = *(const bf16x8*)&At[cur][(wm + mi * 16 + lm) * 32 + lg * 8];
      }
    }
#pragma unroll
    for (int ni = 0; ni < 4; ++ni)
      bfr[ni] = *(const bf16x8*)&Wt[cur][(wn + ni * 16 + lm) * 32 + lg * 8];
    __builtin_amdgcn_s_setprio(1);
#pragma unroll
    for (int mi = 0; mi < MI; ++mi)
#pragma unroll
      for (int ni = 0; ni < 4; ++ni)
        acc[mi][ni] = __builtin_amdgcn_mfma_f32_16x16x32_bf16(
            af[mi], bfr[ni], acc[mi][ni], 0, 0, 0);
    __builtin_amdgcn_s_setprio(0);
    __syncthreads();
  }

  float bv[4];
#pragma unroll
  for (int ni = 0; ni < 4; ++ni) bv[ni] = bias[n0 + wn + ni * 16 + lm];

  if (mode <= 1) {
#pragma unroll
    for (int mi = 0; mi < MI; ++mi)
#pragma unroll
      for (int ni = 0; ni < 4; ++ni) {
        int n = n0 + wn + ni * 16 + lm;
#pragma unroll
        for (int r = 0; r < 4; ++r) {
          int m = m0 + wm + mi * 16 + lg * 4 + r;
          float v = acc[mi][ni][r] + bv[ni];
          if (mode == 1) Cf[(size_t)m * Nn + n] = v;
          else           Cb[(size_t)m * Nn + n] = f2bf(v);
        }
      }
  } else if (mode == 2) {
    // K path: wave's 64 cols = one full head; fused RMSNorm over d
    const int h = (n0 + wn) >> 6;
    float w_[4];
#pragma unroll
    for (int ni = 0; ni < 4; ++ni) w_[ni] = nw[ni * 16 + lm];
#pragma unroll
    for (int mi = 0; mi < MI; ++mi) {
      float t[4][4], ssq[4];
#pragma unroll
      for (int ni = 0; ni < 4; ++ni)
#pragma unroll
        for (int r = 0; r < 4; ++r) t[ni][r] = acc[mi][ni][r] + bv[ni];
#pragma unroll
      for (int r = 0; r < 4; ++r)
        ssq[r] = t[0][r]*t[0][r] + t[1][r]*t[1][r] + t[2][r]*t[2][r] + t[3][r]*t[3][r];
#pragma unroll
      for (int r = 0; r < 4; ++r) {
        ssq[r] += __shfl_xor(ssq[r], 1);
        ssq[r] += __shfl_xor(ssq[r], 2);
        ssq[r] += __shfl_xor(ssq[r], 4);
        ssq[r] += __shfl_xor(ssq[r], 8);
      }
#pragma unroll
      for (int r = 0; r < 4; ++r) {
        float iv = rsqrtf(ssq[r] * (1.f / 64.f) + 1e-5f);
        int n_ = m0 + wm + mi * 16 + lg * 4 + r;
#pragma unroll
        for (int ni = 0; ni < 4; ++ni) {
          int d = ni * 16 + lm;
          Cb[(size_t)h * (N_TOK * HD) + (size_t)n_ * HD + d] = f2bf(t[ni][r] * w_[ni] * iv);
        }
      }
    }
  } else {
    // V path: transpose to Vt[h][d][n]
    const int h = (n0 + wn) >> 6;
#pragma unroll
    for (int mi = 0; mi < MI; ++mi)
#pragma unroll
      for (int ni = 0; ni < 4; ++ni) {
        int d  = ni * 16 + lm;
        int nb = m0 + wm + mi * 16 + lg * 4;
        bf16x4 o;
#pragma unroll
        for (int r = 0; r < 4; ++r) o[r] = (short)f2bf(acc[mi][ni][r] + bv[ni]);
        *(bf16x4*)&Cb[(size_t)h * (HD * N_TOK) + (size_t)d * N_TOK + nb] = o;
      }
  }
}

// fused QKV projections with inline fp32->bf16 A conversion:
// grid (8, 32, 3), 128x128 tiles, z selects {q,k,v}
__global__ __launch_bounds__(256, 3) void qkv_gemm(
    const float* __restrict__ a0, const float* __restrict__ a1,
    const float* __restrict__ a2,
    const unsigned short* __restrict__ w0, const unsigned short* __restrict__ w1,
    const unsigned short* __restrict__ w2,
    const float* __restrict__ b0, const float* __restrict__ b1,
    const float* __restrict__ b2,
    unsigned short* __restrict__ o0, unsigned short* __restrict__ o1,
    unsigned short* __restrict__ o2,
    const float* __restrict__ knw)
{
  const int z = blockIdx.z;
  const float* A32        = (z == 0) ? a0 : (z == 1) ? a1 : a2;
  const unsigned short* W = (z == 0) ? w0 : (z == 1) ? w1 : w2;
  const float* B          = (z == 0) ? b0 : (z == 1) ? b1 : b2;
  unsigned short* O       = (z == 0) ? o0 : (z == 1) ? o1 : o2;
  const int mode          = (z == 0) ? 0 : (z == 1) ? 2 : 3;
  gemm_core<4, true>(nullptr, A32, W, B, O, nullptr, knw, DM, DM, mode,
                     blockIdx.y * 128, blockIdx.x * 128);
}

// out-projection: bf16 A (attn output), f32 out, 128x128 tiles, grid (8, 32)
__global__ __launch_bounds__(256, 3) void out_gemm(
    const unsigned short* __restrict__ A, const unsigned short* __restrict__ W,
    const float* __restrict__ bias, float* __restrict__ Cf)
{
  gemm_core<4, false>(A, nullptr, W, bias, nullptr, Cf, nullptr, DM, DM, 1,
                      blockIdx.y * 128, blockIdx.x * 128);
}

// ---------------- fused RMSNorm(Q) + attention, swapped-QK 32x32, in-block kv-split ----------------
// grid 512 blocks x 512 threads. 8 waves = 2 kv-groups x 4 waves. q-tile 128/block.
// Softmax uses NO max-shift: uniform scale cancels in P/sum(P); args bounded (|s'|<=93).
__global__ __launch_bounds__(512, 4) void attn_kernel(
    const unsigned short* __restrict__ qb,   // (n, 1024) bf16
    const unsigned short* __restrict__ kn,   // Kn[h][kv][64] bf16, normalized
    const unsigned short* __restrict__ vt,   // Vt[h][d][kv] bf16
    const float* __restrict__ wq,            // q_norm_w[64]
    unsigned short* __restrict__ ob)         // (n, 1024) bf16
{
  // [group][buf][K/V][4096 bf16]: 64 KB total
  __shared__ __align__(16) unsigned short SM[2][2][2][4096];

  // XCD-aware decode: XCD x owns heads {2x, 2x+1}
  const int wg   = blockIdx.x;
  const int x_   = wg & 7, rest = wg >> 3;     // rest 0..63
  const int h    = x_ * 2 + (rest & 1);
  const int qt   = rest >> 1;                  // 0..31
  const int tid  = threadIdx.x;
  const int wid  = tid >> 6, lane = tid & 63;
  const int g    = wid >> 2, wv = wid & 3;
  const int l31  = lane & 31, hi = lane >> 5;
  const int sl   = l31 & 7;
  const int qbase = qt * 128 + wv * 32;

  // ---- Q fragments, RMSNorm fused, scaled by log2(e) ----
  bf16x8 qf[4];
  {
    const unsigned short* qp = qb + (size_t)(qbase + l31) * DM + h * HD + hi * 8;
    float qv[32]; float ss = 0.f;
#pragma unroll
    for (int s = 0; s < 4; ++s) {
      bf16x8 raw = *(const bf16x8*)(qp + s * 16);
#pragma unroll
      for (int j = 0; j < 8; ++j) { float f = bf2f(raw[j]); qv[s*8+j] = f; ss += f*f; }
    }
    ss += __shfl_xor(ss, 32);
    float inv = rsqrtf(ss * (1.f / 64.f) + 1e-5f) * 1.44269504f;
#pragma unroll
    for (int s = 0; s < 4; ++s)
#pragma unroll
      for (int j = 0; j < 8; ++j)
        qf[s][j] = (short)f2bf(qv[s*8+j] * wq[s*16 + hi*8 + j] * inv);
  }

  int slot[4];
#pragma unroll
  for (int x = 0; x < 4; ++x) slot[x] = (((2*x + hi) ^ sl) << 4);
  const char* base = (const char*)SM + g * 32768 + l31 * 128;

  // staging sources (pre-swizzled global addresses), 4 chunks/wave within group
  const char* gsrc[4];
  char*       ldst[4];
  long        gstep[4];
  {
    const char* knb = (const char*)kn + (size_t)h * (N_TOK * HD * 2);
    const char* vtb = (const char*)vt + (size_t)h * (HD * N_TOK * 2);
    char* smG = (char*)SM + g * 32768;   // buf 0 of this group
#pragma unroll
    for (int i = 0; i < 4; ++i) {
      int chunk = wv * 4 + i;            // 0..7 K, 8..15 V
      int off   = (chunk & 7) * 1024 + lane * 16;
      int row   = off >> 7;
      int scol  = (off & 127) ^ ((row & 7) << 4);
      if (chunk < 8) {
        gsrc[i]  = knb + (size_t)(g * 2048 + row) * 128 + scol;
        gstep[i] = 64 * 128;
        ldst[i]  = smG + (chunk & 7) * 1024;
      } else {
        gsrc[i]  = vtb + (size_t)row * (N_TOK * 2) + g * 4096 + scol;
        gstep[i] = 64 * 2;
        ldst[i]  = smG + 8192 + (chunk & 7) * 1024;
      }
    }
  }

  f32x16 oacc[2], fz;
#pragma unroll
  for (int r = 0; r < 16; ++r) { oacc[0][r] = 0.f; oacc[1][r] = 0.f; fz[r] = 0.f; }
  float lsp[4] = {0.f, 0.f, 0.f, 0.f};

  // prologue: stage tile 0 into buf 0
#pragma unroll
  for (int i = 0; i < 4; ++i) { gload16(gsrc[i], ldst[i]); gsrc[i] += gstep[i]; }
  __syncthreads();

  const int NT = 2048 / 64;
  for (int it = 0; it < NT; ++it) {
    const int cur = it & 1;
    if (it + 1 < NT) {
      const int nb = cur ^ 1;
#pragma unroll
      for (int i = 0; i < 4; ++i) {
        gload16(gsrc[i], ldst[i] + nb * 16384);
        gsrc[i] += gstep[i];
      }
    }
    const char* KB = base + cur * 16384;
    const char* VB = KB + 8192;

#pragma unroll
    for (int kt = 0; kt < 2; ++kt) {
      // S^T = K Q^T over 32 kv x 32 q
      __builtin_amdgcn_s_setprio(1);
      bf16x8 kf0 = *(const bf16x8*)(KB + kt * 4096 + slot[0]);
      f32x16 sc = __builtin_amdgcn_mfma_f32_32x32x16_bf16(kf0, qf[0], fz, 0, 0, 0);
#pragma unroll
      for (int s = 1; s < 4; ++s) {
        bf16x8 kf = *(const bf16x8*)(KB + kt * 4096 + slot[s]);
        sc = __builtin_amdgcn_mfma_f32_32x32x16_bf16(kf, qf[s], sc, 0, 0, 0);
      }
      __builtin_amdgcn_s_setprio(0);
      // exp2 (no shift), pack, PV
      float e[16];
#pragma unroll
      for (int r = 0; r < 16; ++r) { e[r] = EXP2(sc[r]); lsp[r & 3] += e[r]; }
      unsigned int wpk[4][2];
#pragma unroll
      for (int b = 0; b < 4; ++b) {
        wpk[b][0] = cvtpk(e[4*b+0], e[4*b+1]);
        wpk[b][1] = cvtpk(e[4*b+2], e[4*b+3]);
      }
#pragma unroll
      for (int pr = 0; pr < 2; ++pr) {
        unsigned int x0 = wpk[2*pr][0], x1 = wpk[2*pr][1];
        unsigned int y0 = wpk[2*pr+1][0], y1 = wpk[2*pr+1][1];
        plswap(x0, y0);
        plswap(x1, y1);
        union { unsigned int u[4]; bf16x8 v; } pa;
        pa.u[0] = x0; pa.u[1] = x1; pa.u[2] = y0; pa.u[3] = y1;
        int ks = kt * 2 + pr;
        __builtin_amdgcn_s_setprio(1);
#pragma unroll
        for (int dt = 0; dt < 2; ++dt) {
          bf16x8 vf = *(const bf16x8*)(VB + dt * 4096 + slot[ks]);
          oacc[dt] = __builtin_amdgcn_mfma_f32_32x32x16_bf16(pa.v, vf, oacc[dt], 0, 0, 0);
        }
        __builtin_amdgcn_s_setprio(0);
      }
    }
    __syncthreads();
  }

  // ---- in-block merge of the two kv-groups via LDS, then bf16 write ----
  float ls = (lsp[0] + lsp[1]) + (lsp[2] + lsp[3]);
  ls += __shfl_xor(ls, 32);

  float* ex  = (float*)((char*)SM + 32768);   // 32 KB (group 1's region)
  float* lsx = (float*)SM;                    // 1 KB (group 0's region)
  const int idx = wv * 64 + lane;
  if (g == 1) {
#pragma unroll
    for (int dt = 0; dt < 2; ++dt)
#pragma unroll
      for (int r = 0; r < 16; ++r)
        ex[(dt * 16 + r) * 256 + idx] = oacc[dt][r];
    lsx[idx] = ls;
  }
  __syncthreads();
  if (g == 0) {
#pragma unroll
    for (int dt = 0; dt < 2; ++dt)
#pragma unroll
      for (int r = 0; r < 16; ++r)
        oacc[dt][r] += ex[(dt * 16 + r) * 256 + idx];
    ls += lsx[idx];
    float il = 1.f / ls;
#pragma unroll
    for (int r = 0; r < 16; ++r) {
      int q = (r & 3) + 8 * (r >> 2) + 4 * hi;
      float ilr = __int_as_float(
          __builtin_amdgcn_ds_bpermute(q << 2, __float_as_int(il)));
      unsigned short* op = ob + (size_t)(qbase + q) * DM + h * HD + l31;
      op[0]  = f2bf(oacc[0][r] * ilr);
      op[32] = f2bf(oacc[1][r] * ilr);
    }
  }
}

// ---------------- host ----------------
extern "C" void kernel_launch(void* const* d_in, const int* in_sizes, int n_in,
                              void* d_out, int out_size, void* d_ws, size_t ws_size,
                              hipStream_t stream) {
  const float* query = (const float*)d_in[0];
  const float* key   = (const float*)d_in[1];
  const float* value = (const float*)d_in[2];
  const float* Wq    = (const float*)d_in[3];
  const float* bq    = (const float*)d_in[4];
  const float* Wk    = (const float*)d_in[5];
  const float* bk    = (const float*)d_in[6];
  const float* Wv    = (const float*)d_in[7];
  const float* bv    = (const float*)d_in[8];
  const float* Wo    = (const float*)d_in[9];
  const float* bo    = (const float*)d_in[10];
  const float* qnw   = (const float*)d_in[11];
  const float* knw   = (const float*)d_in[12];

  char* ws = (char*)d_ws;
  const size_t MB = 1024 * 1024;
  unsigned short* qpj = (unsigned short*)(ws + 0 * MB);
  unsigned short* Kn  = (unsigned short*)(ws + 8 * MB);
  unsigned short* Vt  = (unsigned short*)(ws + 16 * MB);
  unsigned short* wob = (unsigned short*)(ws + 24 * MB);
  unsigned short* wqb = (unsigned short*)(ws + 26 * MB);
  unsigned short* wkb = (unsigned short*)(ws + 28 * MB);
  unsigned short* wvb = (unsigned short*)(ws + 30 * MB);
  unsigned short* apj = (unsigned short*)(ws + 56 * MB);

  Cvt4 ca;
  ca.s[0] = Wq; ca.d[0] = wqb;
  ca.s[1] = Wk; ca.d[1] = wkb;
  ca.s[2] = Wv; ca.d[2] = wvb;
  ca.s[3] = Wo; ca.d[3] = wob;
  cvt_w<<<512, 256, 0, stream>>>(ca);

  qkv_gemm<<<dim3(DM / 128, N_TOK / 128, 3), 256, 0, stream>>>(
      query, key, value, wqb, wkb, wvb, bq, bk, bv, qpj, Kn, Vt, knw);

  attn_kernel<<<512, 512, 0, stream>>>(qpj, Kn, Vt, qnw, apj);

  out_gemm<<<dim3(DM / 128, N_TOK / 128), 256, 0, stream>>>(apj, wob, bo, (float*)d_out);
}

// Round 12
// 152.341 us; speedup vs baseline: 4.0810x; 1.0865x over previous
//
#include <hip/hip_runtime.h>
#include <stdint.h>
#include <stddef.h>

#define N_TOK 4096
#define DM    1024
#define NHEAD 16
#define HD    64

typedef __attribute__((ext_vector_type(8)))  short bf16x8;
typedef __attribute__((ext_vector_type(4)))  short bf16x4;
typedef __attribute__((ext_vector_type(4)))  float f32x4;
typedef __attribute__((ext_vector_type(16))) float f32x16;

static __device__ __forceinline__ float bf2f(short u) {
  union { unsigned int i; float f; } c;
  c.i = ((unsigned int)(unsigned short)u) << 16;
  return c.f;
}
static __device__ __forceinline__ unsigned short f2bf(float f) {
  union { float f; unsigned int i; } c; c.f = f;
  unsigned int x = c.i;
  return (unsigned short)((x + 0x7fffu + ((x >> 16) & 1u)) >> 16);
}
static __device__ __forceinline__ unsigned int cvtpk(float lo, float hi) {
  unsigned int d;
  asm("v_cvt_pk_bf16_f32 %0, %1, %2" : "=v"(d) : "v"(lo), "v"(hi));
  return d;
}
static __device__ __forceinline__ void plswap(unsigned int& a, unsigned int& b) {
  asm("v_permlane32_swap_b32 %0, %1" : "+v"(a), "+v"(b));
}
#if __has_builtin(__builtin_amdgcn_exp2f)
#define EXP2(x) __builtin_amdgcn_exp2f(x)
#else
#define EXP2(x) exp2f(x)
#endif
// async global->LDS, 16B/lane; LDS dest wave-uniform base (HW adds lane*16)
static __device__ __forceinline__ void gload16(const void* g, void* l) {
  __builtin_amdgcn_global_load_lds(
      (const __attribute__((address_space(1))) unsigned int*)g,
      (__attribute__((address_space(3))) unsigned int*)l, 16, 0, 0);
}

// ---------------- fused fp32 -> bf16 conversion (all 7 tensors, 1 launch) ----------------
struct Cvt7 { const float* s[7]; unsigned short* d[7]; };
__global__ void cvt_all(Cvt7 a) {
  int u0 = blockIdx.x << 10;              // 1024 units per block, uniform segment
  int seg, off;
  if (u0 < 1572864) { seg = u0 >> 19; off = u0 & 524287; }
  else { int j = u0 - 1572864; seg = 3 + (j >> 17); off = j & 131071; }
  const float* s = a.s[seg];
  unsigned short* dd = a.d[seg];
  int t = off + threadIdx.x;
#pragma unroll
  for (int j = 0; j < 4; ++j, t += 256) {
    const f32x4* sp = (const f32x4*)(s + (size_t)t * 8);
    f32x4 x = sp[0], y = sp[1];
    bf16x8 o;
    o[0] = (short)f2bf(x[0]); o[1] = (short)f2bf(x[1]);
    o[2] = (short)f2bf(x[2]); o[3] = (short)f2bf(x[3]);
    o[4] = (short)f2bf(y[0]); o[5] = (short)f2bf(y[1]);
    o[6] = (short)f2bf(y[2]); o[7] = (short)f2bf(y[3]);
    *(bf16x8*)(dd + (size_t)t * 8) = o;
  }
}

// ---------------- GEMM core: C = A @ W^T + bias, (MI*32)M x 128N tile, dbuf ----------------
// modes: 0 = bf16 row-major out; 1 = f32 row-major out;
//        2 = per-head RMSNorm -> Kn[h][n][64] bf16;  3 = transpose -> Vt[h][d][n] bf16
template <int MI>
static __device__ __forceinline__ void gemm_core(
    const unsigned short* __restrict__ A,
    const unsigned short* __restrict__ W,
    const float* __restrict__ bias,
    unsigned short* __restrict__ Cb,
    float* __restrict__ Cf,
    const float* __restrict__ nw,
    int Nn, int K, int mode, int m0, int n0)
{
  __shared__ __align__(16) unsigned short At[2][MI * 1024];  // (MI*32) x 32
  __shared__ __align__(16) unsigned short Wt[2][128 * 32];
  const int tid  = threadIdx.x;
  const int wid  = tid >> 6, lane = tid & 63;
  const int lm   = lane & 15, lg = lane >> 4;
  const int wm   = (wid >> 1) * (MI * 16), wn = (wid & 1) * 64;
  const int CPW  = (MI * 2 + 8) / 4;       // chunks per wave

  f32x4 acc[MI][4];
#pragma unroll
  for (int i = 0; i < MI; ++i)
#pragma unroll
    for (int j = 0; j < 4; ++j) acc[i][j] = f32x4{0.f, 0.f, 0.f, 0.f};

  auto stage = [&](int b, int k0) {
#pragma unroll
    for (int i = 0; i < CPW; ++i) {
      int c = wid * CPW + i;
      if (c < MI * 2)
        gload16(A + (size_t)(m0 + c * 16 + (lane >> 2)) * K + k0 + (lane & 3) * 8,
                (char*)At + b * (MI * 2048) + c * 1024);
      else
        gload16(W + (size_t)(n0 + (c - MI * 2) * 16 + (lane >> 2)) * K + k0 + (lane & 3) * 8,
                (char*)Wt + b * 8192 + (c - MI * 2) * 1024);
    }
  };

  const int nk = K >> 5;
  stage(0, 0);
  __syncthreads();
  for (int kt = 0; kt < nk; ++kt) {
    const int cur = kt & 1;
    if (kt + 1 < nk) stage(cur ^ 1, (kt + 1) << 5);

    bf16x8 af[MI], bfr[4];
#pragma unroll
    for (int mi = 0; mi < MI; ++mi)
      af[mi] = *(const bf16x8*)&At[cur][(wm + mi * 16 + lm) * 32 + lg * 8];
#pragma unroll
    for (int ni = 0; ni < 4; ++ni)
      bfr[ni] = *(const bf16x8*)&Wt[cur][(wn + ni * 16 + lm) * 32 + lg * 8];
    __builtin_amdgcn_s_setprio(1);
#pragma unroll
    for (int mi = 0; mi < MI; ++mi)
#pragma unroll
      for (int ni = 0; ni < 4; ++ni)
        acc[mi][ni] = __builtin_amdgcn_mfma_f32_16x16x32_bf16(
            af[mi], bfr[ni], acc[mi][ni], 0, 0, 0);
    __builtin_amdgcn_s_setprio(0);
    __syncthreads();
  }

  float bv[4];
#pragma unroll
  for (int ni = 0; ni < 4; ++ni) bv[ni] = bias[n0 + wn + ni * 16 + lm];

  if (mode <= 1) {
#pragma unroll
    for (int mi = 0; mi < MI; ++mi)
#pragma unroll
      for (int ni = 0; ni < 4; ++ni) {
        int n = n0 + wn + ni * 16 + lm;
#pragma unroll
        for (int r = 0; r < 4; ++r) {
          int m = m0 + wm + mi * 16 + lg * 4 + r;
          float v = acc[mi][ni][r] + bv[ni];
          if (mode == 1) Cf[(size_t)m * Nn + n] = v;
          else           Cb[(size_t)m * Nn + n] = f2bf(v);
        }
      }
  } else if (mode == 2) {
    // K path: wave's 64 cols = one full head; fused RMSNorm over d
    const int h = (n0 + wn) >> 6;
    float w_[4];
#pragma unroll
    for (int ni = 0; ni < 4; ++ni) w_[ni] = nw[ni * 16 + lm];
#pragma unroll
    for (int mi = 0; mi < MI; ++mi) {
      float t[4][4], ssq[4];
#pragma unroll
      for (int ni = 0; ni < 4; ++ni)
#pragma unroll
        for (int r = 0; r < 4; ++r) t[ni][r] = acc[mi][ni][r] + bv[ni];
#pragma unroll
      for (int r = 0; r < 4; ++r)
        ssq[r] = t[0][r]*t[0][r] + t[1][r]*t[1][r] + t[2][r]*t[2][r] + t[3][r]*t[3][r];
#pragma unroll
      for (int r = 0; r < 4; ++r) {
        ssq[r] += __shfl_xor(ssq[r], 1);
        ssq[r] += __shfl_xor(ssq[r], 2);
        ssq[r] += __shfl_xor(ssq[r], 4);
        ssq[r] += __shfl_xor(ssq[r], 8);
      }
#pragma unroll
      for (int r = 0; r < 4; ++r) {
        float iv = rsqrtf(ssq[r] * (1.f / 64.f) + 1e-5f);
        int n_ = m0 + wm + mi * 16 + lg * 4 + r;
#pragma unroll
        for (int ni = 0; ni < 4; ++ni) {
          int d = ni * 16 + lm;
          Cb[(size_t)h * (N_TOK * HD) + (size_t)n_ * HD + d] = f2bf(t[ni][r] * w_[ni] * iv);
        }
      }
    }
  } else {
    // V path: transpose to Vt[h][d][n]
    const int h = (n0 + wn) >> 6;
#pragma unroll
    for (int mi = 0; mi < MI; ++mi)
#pragma unroll
      for (int ni = 0; ni < 4; ++ni) {
        int d  = ni * 16 + lm;
        int nb = m0 + wm + mi * 16 + lg * 4;
        bf16x4 o;
#pragma unroll
        for (int r = 0; r < 4; ++r) o[r] = (short)f2bf(acc[mi][ni][r] + bv[ni]);
        *(bf16x4*)&Cb[(size_t)h * (HD * N_TOK) + (size_t)d * N_TOK + nb] = o;
      }
  }
}

// fused QKV projections: grid (8, 32, 3), 128x128 tiles, z selects {q,k,v}
// (256,4): cap VGPR at 128 -> 4 blocks/CU (LDS 24KB is not the binder).
// Spill sentinel: qkv WRITE_SIZE balloons if the cap forces scratch.
__global__ __launch_bounds__(256, 4) void qkv_gemm(
    const unsigned short* __restrict__ a0, const unsigned short* __restrict__ a1,
    const unsigned short* __restrict__ a2,
    const unsigned short* __restrict__ w0, const unsigned short* __restrict__ w1,
    const unsigned short* __restrict__ w2,
    const float* __restrict__ b0, const float* __restrict__ b1,
    const float* __restrict__ b2,
    unsigned short* __restrict__ o0, unsigned short* __restrict__ o1,
    unsigned short* __restrict__ o2,
    const float* __restrict__ knw)
{
  const int z = blockIdx.z;
  const unsigned short* A = (z == 0) ? a0 : (z == 1) ? a1 : a2;
  const unsigned short* W = (z == 0) ? w0 : (z == 1) ? w1 : w2;
  const float* B          = (z == 0) ? b0 : (z == 1) ? b1 : b2;
  unsigned short* O       = (z == 0) ? o0 : (z == 1) ? o1 : o2;
  const int mode          = (z == 0) ? 0 : (z == 1) ? 2 : 3;
  gemm_core<4>(A, W, B, O, nullptr, knw, DM, DM, mode,
               blockIdx.y * 128, blockIdx.x * 128);
}

// out-projection: f32 out, 128x128 tiles, grid (8, 32)
__global__ __launch_bounds__(256, 3) void out_gemm(
    const unsigned short* __restrict__ A, const unsigned short* __restrict__ W,
    const float* __restrict__ bias, float* __restrict__ Cf)
{
  gemm_core<4>(A, W, bias, nullptr, Cf, nullptr, DM, DM, 1,
               blockIdx.y * 128, blockIdx.x * 128);
}

// ---------------- fused RMSNorm(Q) + attention, swapped-QK 32x32, in-block kv-split ----------------
// grid 512 blocks x 512 threads. 8 waves = 2 kv-groups x 4 waves. q-tile 128/block.
// Softmax uses NO max-shift: uniform scale cancels in P/sum(P); args bounded (|s'|<=93).
__global__ __launch_bounds__(512, 4) void attn_kernel(
    const unsigned short* __restrict__ qb,   // (n, 1024) bf16
    const unsigned short* __restrict__ kn,   // Kn[h][kv][64] bf16, normalized
    const unsigned short* __restrict__ vt,   // Vt[h][d][kv] bf16
    const float* __restrict__ wq,            // q_norm_w[64]
    unsigned short* __restrict__ ob)         // (n, 1024) bf16
{
  // [group][buf][K/V][4096 bf16]: 64 KB total
  __shared__ __align__(16) unsigned short SM[2][2][2][4096];

  // XCD-aware decode: XCD x owns heads {2x, 2x+1}
  const int wg   = blockIdx.x;
  const int x_   = wg & 7, rest = wg >> 3;     // rest 0..63
  const int h    = x_ * 2 + (rest & 1);
  const int qt   = rest >> 1;                  // 0..31
  const int tid  = threadIdx.x;
  const int wid  = tid >> 6, lane = tid & 63;
  const int g    = wid >> 2, wv = wid & 3;
  const int l31  = lane & 31, hi = lane >> 5;
  const int sl   = l31 & 7;
  const int qbase = qt * 128 + wv * 32;

  // ---- Q fragments, RMSNorm fused, scaled by log2(e) ----
  bf16x8 qf[4];
  {
    const unsigned short* qp = qb + (size_t)(qbase + l31) * DM + h * HD + hi * 8;
    float qv[32]; float ss = 0.f;
#pragma unroll
    for (int s = 0; s < 4; ++s) {
      bf16x8 raw = *(const bf16x8*)(qp + s * 16);
#pragma unroll
      for (int j = 0; j < 8; ++j) { float f = bf2f(raw[j]); qv[s*8+j] = f; ss += f*f; }
    }
    ss += __shfl_xor(ss, 32);
    float inv = rsqrtf(ss * (1.f / 64.f) + 1e-5f) * 1.44269504f;
#pragma unroll
    for (int s = 0; s < 4; ++s)
#pragma unroll
      for (int j = 0; j < 8; ++j)
        qf[s][j] = (short)f2bf(qv[s*8+j] * wq[s*16 + hi*8 + j] * inv);
  }

  int slot[4];
#pragma unroll
  for (int x = 0; x < 4; ++x) slot[x] = (((2*x + hi) ^ sl) << 4);
  const char* base = (const char*)SM + g * 32768 + l31 * 128;

  // staging sources (pre-swizzled global addresses), 4 chunks/wave within group
  const char* gsrc[4];
  char*       ldst[4];
  long        gstep[4];
  {
    const char* knb = (const char*)kn + (size_t)h * (N_TOK * HD * 2);
    const char* vtb = (const char*)vt + (size_t)h * (HD * N_TOK * 2);
    char* smG = (char*)SM + g * 32768;   // buf 0 of this group
#pragma unroll
    for (int i = 0; i < 4; ++i) {
      int chunk = wv * 4 + i;            // 0..7 K, 8..15 V
      int off   = (chunk & 7) * 1024 + lane * 16;
      int row   = off >> 7;
      int scol  = (off & 127) ^ ((row & 7) << 4);
      if (chunk < 8) {
        gsrc[i]  = knb + (size_t)(g * 2048 + row) * 128 + scol;
        gstep[i] = 64 * 128;
        ldst[i]  = smG + (chunk & 7) * 1024;
      } else {
        gsrc[i]  = vtb + (size_t)row * (N_TOK * 2) + g * 4096 + scol;
        gstep[i] = 64 * 2;
        ldst[i]  = smG + 8192 + (chunk & 7) * 1024;
      }
    }
  }

  f32x16 oacc[2], fz;
#pragma unroll
  for (int r = 0; r < 16; ++r) { oacc[0][r] = 0.f; oacc[1][r] = 0.f; fz[r] = 0.f; }
  float lsp[4] = {0.f, 0.f, 0.f, 0.f};

  // prologue: stage tile 0 into buf 0
#pragma unroll
  for (int i = 0; i < 4; ++i) { gload16(gsrc[i], ldst[i]); gsrc[i] += gstep[i]; }
  __syncthreads();

  const int NT = 2048 / 64;
  for (int it = 0; it < NT; ++it) {
    const int cur = it & 1;
    if (it + 1 < NT) {
      const int nb = cur ^ 1;
#pragma unroll
      for (int i = 0; i < 4; ++i) {
        gload16(gsrc[i], ldst[i] + nb * 16384);
        gsrc[i] += gstep[i];
      }
    }
    const char* KB = base + cur * 16384;
    const char* VB = KB + 8192;

#pragma unroll
    for (int kt = 0; kt < 2; ++kt) {
      // S^T = K Q^T over 32 kv x 32 q
      __builtin_amdgcn_s_setprio(1);
      bf16x8 kf0 = *(const bf16x8*)(KB + kt * 4096 + slot[0]);
      f32x16 sc = __builtin_amdgcn_mfma_f32_32x32x16_bf16(kf0, qf[0], fz, 0, 0, 0);
#pragma unroll
      for (int s = 1; s < 4; ++s) {
        bf16x8 kf = *(const bf16x8*)(KB + kt * 4096 + slot[s]);
        sc = __builtin_amdgcn_mfma_f32_32x32x16_bf16(kf, qf[s], sc, 0, 0, 0);
      }
      __builtin_amdgcn_s_setprio(0);
      // exp2 (no shift), pack, PV
      float e[16];
#pragma unroll
      for (int r = 0; r < 16; ++r) { e[r] = EXP2(sc[r]); lsp[r & 3] += e[r]; }
      unsigned int wpk[4][2];
#pragma unroll
      for (int b = 0; b < 4; ++b) {
        wpk[b][0] = cvtpk(e[4*b+0], e[4*b+1]);
        wpk[b][1] = cvtpk(e[4*b+2], e[4*b+3]);
      }
#pragma unroll
      for (int pr = 0; pr < 2; ++pr) {
        unsigned int x0 = wpk[2*pr][0], x1 = wpk[2*pr][1];
        unsigned int y0 = wpk[2*pr+1][0], y1 = wpk[2*pr+1][1];
        plswap(x0, y0);
        plswap(x1, y1);
        union { unsigned int u[4]; bf16x8 v; } pa;
        pa.u[0] = x0; pa.u[1] = x1; pa.u[2] = y0; pa.u[3] = y1;
        int ks = kt * 2 + pr;
        __builtin_amdgcn_s_setprio(1);
#pragma unroll
        for (int dt = 0; dt < 2; ++dt) {
          bf16x8 vf = *(const bf16x8*)(VB + dt * 4096 + slot[ks]);
          oacc[dt] = __builtin_amdgcn_mfma_f32_32x32x16_bf16(pa.v, vf, oacc[dt], 0, 0, 0);
        }
        __builtin_amdgcn_s_setprio(0);
      }
    }
    __syncthreads();
  }

  // ---- in-block merge of the two kv-groups via LDS, then bf16 write ----
  float ls = (lsp[0] + lsp[1]) + (lsp[2] + lsp[3]);
  ls += __shfl_xor(ls, 32);

  float* ex  = (float*)((char*)SM + 32768);   // 32 KB (group 1's region)
  float* lsx = (float*)SM;                    // 1 KB (group 0's region)
  const int idx = wv * 64 + lane;
  if (g == 1) {
#pragma unroll
    for (int dt = 0; dt < 2; ++dt)
#pragma unroll
      for (int r = 0; r < 16; ++r)
        ex[(dt * 16 + r) * 256 + idx] = oacc[dt][r];
    lsx[idx] = ls;
  }
  __syncthreads();
  if (g == 0) {
#pragma unroll
    for (int dt = 0; dt < 2; ++dt)
#pragma unroll
      for (int r = 0; r < 16; ++r)
        oacc[dt][r] += ex[(dt * 16 + r) * 256 + idx];
    ls += lsx[idx];
    float il = 1.f / ls;
#pragma unroll
    for (int r = 0; r < 16; ++r) {
      int q = (r & 3) + 8 * (r >> 2) + 4 * hi;
      float ilr = __int_as_float(
          __builtin_amdgcn_ds_bpermute(q << 2, __float_as_int(il)));
      unsigned short* op = ob + (size_t)(qbase + q) * DM + h * HD + l31;
      op[0]  = f2bf(oacc[0][r] * ilr);
      op[32] = f2bf(oacc[1][r] * ilr);
    }
  }
}

// ---------------- host ----------------
extern "C" void kernel_launch(void* const* d_in, const int* in_sizes, int n_in,
                              void* d_out, int out_size, void* d_ws, size_t ws_size,
                              hipStream_t stream) {
  const float* query = (const float*)d_in[0];
  const float* key   = (const float*)d_in[1];
  const float* value = (const float*)d_in[2];
  const float* Wq    = (const float*)d_in[3];
  const float* bq    = (const float*)d_in[4];
  const float* Wk    = (const float*)d_in[5];
  const float* bk    = (const float*)d_in[6];
  const float* Wv    = (const float*)d_in[7];
  const float* bv    = (const float*)d_in[8];
  const float* Wo    = (const float*)d_in[9];
  const float* bo    = (const float*)d_in[10];
  const float* qnw   = (const float*)d_in[11];
  const float* knw   = (const float*)d_in[12];

  char* ws = (char*)d_ws;
  const size_t MB = 1024 * 1024;
  unsigned short* qpj = (unsigned short*)(ws + 0 * MB);
  unsigned short* Kn  = (unsigned short*)(ws + 8 * MB);
  unsigned short* Vt  = (unsigned short*)(ws + 16 * MB);
  unsigned short* wob = (unsigned short*)(ws + 24 * MB);
  unsigned short* wqb = (unsigned short*)(ws + 26 * MB);
  unsigned short* wkb = (unsigned short*)(ws + 28 * MB);
  unsigned short* wvb = (unsigned short*)(ws + 30 * MB);
  unsigned short* qbf = (unsigned short*)(ws + 32 * MB);
  unsigned short* kbf = (unsigned short*)(ws + 40 * MB);
  unsigned short* vbf = (unsigned short*)(ws + 48 * MB);
  unsigned short* apj = (unsigned short*)(ws + 56 * MB);

  Cvt7 ca;
  ca.s[0] = query; ca.d[0] = qbf;
  ca.s[1] = key;   ca.d[1] = kbf;
  ca.s[2] = value; ca.d[2] = vbf;
  ca.s[3] = Wq;    ca.d[3] = wqb;
  ca.s[4] = Wk;    ca.d[4] = wkb;
  ca.s[5] = Wv;    ca.d[5] = wvb;
  ca.s[6] = Wo;    ca.d[6] = wob;
  cvt_all<<<2048, 256, 0, stream>>>(ca);

  qkv_gemm<<<dim3(DM / 128, N_TOK / 128, 3), 256, 0, stream>>>(
      qbf, kbf, vbf, wqb, wkb, wvb, bq, bk, bv, qpj, Kn, Vt, knw);

  attn_kernel<<<512, 512, 0, stream>>>(qpj, Kn, Vt, qnw, apj);

  out_gemm<<<dim3(DM / 128, N_TOK / 128), 256, 0, stream>>>(apj, wob, bo, (float*)d_out);
}